// Round 13
// baseline (254.925 us; speedup 1.0000x reference)
//
#include <hip/hip_runtime.h>
#include <math.h>

#define NN 50000      // nodes
#define DD 128        // embedding dim
#define K2D 256       // 2*D (pair width)
#define HH 256        // hidden
#define EE 400000     // edges
#define TE 64         // rows per block (res / fallback det)
#define TD 32         // edges per tile in pipelined det (33KB LDS -> 4 blk/CU)
#define RT 32         // flagged edges per refine tile
#define PST 260       // padded fp32 LDS row stride
#define TAU  0.005f   // |z_bf16| band -> fp32 refine (sigma(dz)~4e-4, >=12 sigma)
#define TAU2 5e-5f    // |z_fp32| band -> fp64 decide (inline)
#define DGRID 1024    // det_pipe grid: 4 blocks/CU x 256 CU

typedef __attribute__((ext_vector_type(8))) short bf16x8;
typedef __attribute__((ext_vector_type(4))) float f32x4;
typedef unsigned int uint;
typedef unsigned short ushort;

typedef __attribute__((address_space(3))) void lds_void_t;
typedef __attribute__((address_space(1))) void g1_void_t;

__device__ __forceinline__ ushort f2bf(float x) {
    uint u = __builtin_bit_cast(uint, x);
    u = (u + 0x7FFFu + ((u >> 16) & 1u)) >> 16;   // RNE
    return (ushort)u;
}

// LDS A-tile in MFMA A-fragment order (round-2 derivation):
// (r,k) -> sid=(r>>4)*8+(k>>5), lane=((k>>3)&3)*16+(r&15), j=k&7
__device__ __forceinline__ int stageOff(int r, int k) {
    return ((r >> 4) * 8 + (k >> 5)) * 512 + ((((k >> 3) & 3) << 4) + (r & 15)) * 8 + (k & 7);
}

__device__ __forceinline__ void swz_unit(const float* __restrict__ W,
                                         ushort* __restrict__ out,
                                         int N, int Kt, int unit, int l)
{
    const int n = unit / Kt, t = unit - n * Kt;
    const int row0 = t * 32 + (l >> 4) * 8;
    const int col = n * 16 + (l & 15);
    ushort tmp[8];
#pragma unroll
    for (int j = 0; j < 8; ++j) tmp[j] = f2bf(W[(row0 + j) * N + col]);
    uint4 p;
    p.x = (uint)tmp[0] | ((uint)tmp[1] << 16);
    p.y = (uint)tmp[2] | ((uint)tmp[3] << 16);
    p.z = (uint)tmp[4] | ((uint)tmp[5] << 16);
    p.w = (uint)tmp[6] | ((uint)tmp[7] << 16);
    *(uint4*)(out + ((size_t)unit * 64 + l) * 8) = p;
}

// ---------------------------------------------------------------------------
// PREP: emb fp32->bf16 (blocks 0..3124) + weight swizzles (blocks 3125..3204)
// ---------------------------------------------------------------------------
__global__ __launch_bounds__(256) void prep_kernel(
    const float* __restrict__ emb, ushort* __restrict__ embbf, int doConv,
    const float* __restrict__ Wd1, ushort* __restrict__ wd1s,
    const float* __restrict__ Wr1, ushort* __restrict__ wr1s,
    const float* __restrict__ Wr2, ushort* __restrict__ wr2s)
{
    const int gid = blockIdx.x;
    const int tid = threadIdx.x;
    if (gid < 3125) {
        if (!doConv) return;
        const int i = gid * 256 + tid;            // 3125*256 == NN*DD/8 exactly
        const float4 a = ((const float4*)emb)[(size_t)i * 2];
        const float4 b = ((const float4*)emb)[(size_t)i * 2 + 1];
        uint4 p;
        p.x = (uint)f2bf(a.x) | ((uint)f2bf(a.y) << 16);
        p.y = (uint)f2bf(a.z) | ((uint)f2bf(a.w) << 16);
        p.z = (uint)f2bf(b.x) | ((uint)f2bf(b.y) << 16);
        p.w = (uint)f2bf(b.z) | ((uint)f2bf(b.w) << 16);
        *(uint4*)(embbf + (size_t)i * 8) = p;
        return;
    }
    const int sub = tid >> 6, l = tid & 63;
    if (gid < 3125 + 32) {
        swz_unit(Wd1, wd1s, HH, 8, (gid - 3125) * 4 + sub, l);
    } else if (gid < 3125 + 64) {
        swz_unit(Wr1, wr1s, HH, 8, (gid - 3125 - 32) * 4 + sub, l);
    } else {
        swz_unit(Wr2, wr2s, DD, 8, (gid - 3125 - 64) * 4 + sub, l);
    }
}

// ---------------------------------------------------------------------------
// PIPELINED persistent detector, TD=32 tiles (33KB LDS -> 4 blocks/CU).
// Round-11 counted-vmcnt double-buffer + round-6 stage/compute geometry.
// Per wave: STAGE issues 4 global_load_lds; vmcnt(4) leaves exactly the
// next tile's loads in flight and drains all older ops. Race-free.
// ---------------------------------------------------------------------------
__global__ __launch_bounds__(256) void det_pipe(
    const ushort* __restrict__ embbf,
    const int* __restrict__ srcIdx, const int* __restrict__ dstIdx,
    const ushort* __restrict__ w1s, const float* __restrict__ b1,
    const float* __restrict__ W2, const float* __restrict__ b2p,
    float* __restrict__ scores,
    int* __restrict__ last,
    int* __restrict__ flagCount, int* __restrict__ flagList, int flagCap)
{
    __shared__ __align__(16) ushort A[2][TD * K2D];   // 2 x 16 KB, frag order
    __shared__ float zp[2][4][TD];                    // 1 KB
    const int tid = threadIdx.x;
    const int wv = tid >> 6;
    const int lane = tid & 63;
    const int lc = lane & 15, lg = lane >> 4;
    const int nT = EE / TD;                            // 12500
    const int stride = gridDim.x;

    float b1v[4], w2v[4];
#pragma unroll
    for (int n = 0; n < 4; ++n) {
        const int col = wv * 64 + n * 16 + lc;
        b1v[n] = b1[col];
        w2v[n] = W2[col];
    }
    const float b2v = *b2p;
    const ushort* wbase = w1s + (size_t)(wv * 4) * 8 * 512;

    // wave wv stages subtiles sid = wv*4+s (m-tile wv>>1, src/dst half wv&1)
    const int sm = wv >> 1, shalf = wv & 1;
    auto STAGE = [&](int T, int bp) {
        const int e = T * TD + sm * 16 + lc;
        const int node = shalf ? dstIdx[e] : srcIdx[e];
        const ushort* gb = embbf + (size_t)node * DD + lg * 8;
#pragma unroll
        for (int s = 0; s < 4; ++s)
            __builtin_amdgcn_global_load_lds((const g1_void_t*)(gb + s * 32),
                                             (lds_void_t*)&A[bp][(wv * 4 + s) * 512],
                                             16, 0, 0);
    };

    int T = blockIdx.x;
    int cur = 0;
    if (T >= nT) return;
    STAGE(T, 0);                                       // prologue: 4 in flight

    for (; T < nT; T += stride) {
        const int Tn = T + stride;
        if (Tn < nT) {
            STAGE(Tn, cur ^ 1);                        // +4 (newest)
            asm volatile("s_waitcnt vmcnt(4)" ::: "memory");   // tile T landed
        } else {
            asm volatile("s_waitcnt vmcnt(0)" ::: "memory");   // tail drain
        }
        __builtin_amdgcn_sched_barrier(0);
        __builtin_amdgcn_s_barrier();                  // all waves: A[cur] ready
        __builtin_amdgcn_sched_barrier(0);

        // ---- compute tile T from A[cur] ----
        f32x4 acc[2][4] = {};
#pragma unroll
        for (int t = 0; t < 8; ++t) {
            const bf16x8 a0 = *(const bf16x8*)&A[cur][(0 * 8 + t) * 512 + lane * 8];
            const bf16x8 a1 = *(const bf16x8*)&A[cur][(1 * 8 + t) * 512 + lane * 8];
#pragma unroll
            for (int n = 0; n < 4; ++n) {
                acc[0][n] = __builtin_amdgcn_mfma_f32_16x16x32_bf16(a0, *(const bf16x8*)(wbase + (size_t)(n * 8 + t) * 512 + lane * 8), acc[0][n], 0, 0, 0);
                acc[1][n] = __builtin_amdgcn_mfma_f32_16x16x32_bf16(a1, *(const bf16x8*)(wbase + (size_t)(n * 8 + t) * 512 + lane * 8), acc[1][n], 0, 0, 0);
            }
        }

        // layer-2 partials over this wave's 64 cols
#pragma unroll
        for (int mm = 0; mm < 2; ++mm) {
            float pz[4];
#pragma unroll
            for (int r = 0; r < 4; ++r) {
                float s = 0.f;
#pragma unroll
                for (int n = 0; n < 4; ++n)
                    s = fmaf(fmaxf(acc[mm][n][r] + b1v[n], 0.f), w2v[n], s);
                pz[r] = s;
            }
#pragma unroll
            for (int msk = 1; msk <= 8; msk <<= 1)
#pragma unroll
                for (int r = 0; r < 4; ++r)
                    pz[r] += __shfl_xor(pz[r], msk, 64);
            if (lc == 0) {
#pragma unroll
                for (int r = 0; r < 4; ++r)
                    zp[cur][wv][mm * 16 + lg * 4 + r] = pz[r];
            }
        }

        asm volatile("s_waitcnt lgkmcnt(0)" ::: "memory");     // zp visible
        __builtin_amdgcn_sched_barrier(0);
        __builtin_amdgcn_s_barrier();
        __builtin_amdgcn_sched_barrier(0);

        // ---- epilogue (8 lanes/wave) overlaps next iteration's STAGE ----
        if (lane < 8) {
            const int row = wv * 8 + lane;
            const int e = T * TD + row;
            const float z = zp[cur][0][row] + zp[cur][1][row] +
                            zp[cur][2][row] + zp[cur][3][row] + b2v;
            scores[e] = 1.0f / (1.0f + expf(-z));
            bool deferred = false;
            if (fabsf(z) < TAU) {
                const int slot = atomicAdd(flagCount, 1);
                if (slot < flagCap) { flagList[slot] = e; deferred = true; }
            }
            if (!deferred && z > 0.0f) {
                atomicMax(&last[srcIdx[e]], e + 1);
                atomicMax(&last[dstIdx[e]], e + 1);
            }
        }
        cur ^= 1;
    }
}

// ---------------------------------------------------------------------------
// Fallback detector (round-10 proven, fp32 staging) for tiny workspaces.
// ---------------------------------------------------------------------------
__global__ __launch_bounds__(256) void det_kernel(
    const float* __restrict__ emb,
    const int* __restrict__ srcIdx, const int* __restrict__ dstIdx,
    const ushort* __restrict__ w1s, const float* __restrict__ b1,
    const float* __restrict__ W2, const float* __restrict__ b2p,
    float* __restrict__ scores,
    int* __restrict__ last,
    int* __restrict__ flagCount, int* __restrict__ flagList, int flagCap)
{
    __shared__ __align__(16) ushort A_lds[TE * K2D];
    __shared__ float zp[256];
    const int tid = threadIdx.x;
    const int e0 = blockIdx.x * TE;
    {
        const int r = tid >> 2, q = tid & 3;
        const int e = e0 + r;
        const int node = (q < 2) ? srcIdx[e] : dstIdx[e];
        const float4* s4 = (const float4*)(emb + (size_t)node * DD + (q & 1) * 64);
#pragma unroll
        for (int u = 0; u < 16; ++u) {
            const float4 v = s4[u];
            const int k0 = q * 64 + u * 4;
            uint2 p;
            p.x = (uint)f2bf(v.x) | ((uint)f2bf(v.y) << 16);
            p.y = (uint)f2bf(v.z) | ((uint)f2bf(v.w) << 16);
            *(uint2*)&A_lds[stageOff(r, k0)] = p;
        }
    }
    __syncthreads();

    const int wv = tid >> 6;
    const int lane = tid & 63;
    const int lc = lane & 15, lg = lane >> 4;

    f32x4 acc[4][4] = {};
    const ushort* wbase = w1s + (size_t)(wv * 4) * 8 * 512;
#pragma unroll 2
    for (int t = 0; t < 8; ++t) {
        bf16x8 af[4], bfr[4];
#pragma unroll
        for (int m = 0; m < 4; ++m)
            af[m] = *(const bf16x8*)&A_lds[(m * 8 + t) * 512 + lane * 8];
#pragma unroll
        for (int n = 0; n < 4; ++n)
            bfr[n] = *(const bf16x8*)(wbase + (n * 8 + t) * 512 + lane * 8);
#pragma unroll
        for (int m = 0; m < 4; ++m)
#pragma unroll
            for (int n = 0; n < 4; ++n)
                acc[m][n] = __builtin_amdgcn_mfma_f32_16x16x32_bf16(af[m], bfr[n], acc[m][n], 0, 0, 0);
    }
    float b1v[4], w2v[4];
#pragma unroll
    for (int n = 0; n < 4; ++n) {
        const int col = wv * 64 + n * 16 + lc;
        b1v[n] = b1[col];
        w2v[n] = W2[col];
    }
    float pz[4][4];
#pragma unroll
    for (int m = 0; m < 4; ++m)
#pragma unroll
        for (int r = 0; r < 4; ++r) {
            float s = 0.f;
#pragma unroll
            for (int n = 0; n < 4; ++n)
                s = fmaf(fmaxf(acc[m][n][r] + b1v[n], 0.f), w2v[n], s);
            pz[m][r] = s;
        }
#pragma unroll
    for (int msk = 1; msk <= 8; msk <<= 1)
#pragma unroll
        for (int m = 0; m < 4; ++m)
#pragma unroll
            for (int r = 0; r < 4; ++r)
                pz[m][r] += __shfl_xor(pz[m][r], msk, 64);
    if (lc == 0) {
#pragma unroll
        for (int m = 0; m < 4; ++m)
#pragma unroll
            for (int r = 0; r < 4; ++r)
                zp[wv * 64 + m * 16 + lg * 4 + r] = pz[m][r];
    }
    __syncthreads();
    if (tid < 64) {
        const int e = e0 + tid;
        const float z = zp[tid] + zp[64 + tid] + zp[128 + tid] + zp[192 + tid] + *b2p;
        scores[e] = 1.0f / (1.0f + expf(-z));
        bool deferred = false;
        if (fabsf(z) < TAU) {
            const int slot = atomicAdd(flagCount, 1);
            if (slot < flagCap) { flagList[slot] = e; deferred = true; }
        }
        if (!deferred && z > 0.0f) {
            atomicMax(&last[srcIdx[e]], e + 1);
            atomicMax(&last[dstIdx[e]], e + 1);
        }
    }
}

// ---------------------------------------------------------------------------
// Refine (fp32 tiled GEMM over flagged edges) + inline fp64 final decision.
// ---------------------------------------------------------------------------
__global__ __launch_bounds__(256) void refine_kernel(
    const float* __restrict__ emb,
    const int* __restrict__ srcIdx, const int* __restrict__ dstIdx,
    const float* __restrict__ W1, const float* __restrict__ b1,
    const float* __restrict__ W2, const float* __restrict__ b2p,
    int* __restrict__ last,
    const int* __restrict__ flagCount, const int* __restrict__ flagList,
    int flagCap)
{
    __shared__ __align__(16) float P[RT * PST];   // 33.3 KB
    __shared__ int eL[RT];
    __shared__ float zs[RT];
    __shared__ int need64[RT];
    __shared__ double wsumd[4];
    const int tid = threadIdx.x;
    const int cnt = min(*flagCount, flagCap);
    const int nTiles = (cnt + RT - 1) / RT;
    const float b2v = *b2p;

    for (int T = blockIdx.x; T < nTiles; T += gridDim.x) {
        if (tid < RT) {
            const int idx = T * RT + tid;
            eL[tid] = flagList[min(idx, cnt - 1)];
            need64[tid] = 0;
        }
        __syncthreads();
        {
            const int i = tid >> 3, q = tid & 7;
            const int e = eL[i];
            const int node = (q < 4) ? srcIdx[e] : dstIdx[e];
            const float4* s4 = (const float4*)(emb + (size_t)node * DD + (q & 3) * 32);
            float4* d4 = (float4*)(P + i * PST + q * 32);
#pragma unroll
            for (int t = 0; t < 8; ++t) d4[t] = s4[t];
        }
        __syncthreads();

        const int rowg = tid >> 5;
        const int colg = tid & 31;
        const int c0 = colg * 8;

        float acc[4][8];
#pragma unroll
        for (int c = 0; c < 8; ++c) {
            const float bv = b1[c0 + c];
#pragma unroll
            for (int r = 0; r < 4; ++r) acc[r][c] = bv;
        }
        for (int kk = 0; kk < K2D; kk += 4) {
            float af[4][4];
#pragma unroll
            for (int r = 0; r < 4; ++r) {
                const float4 v = *(const float4*)&P[(rowg * 4 + r) * PST + kk];
                af[r][0] = v.x; af[r][1] = v.y; af[r][2] = v.z; af[r][3] = v.w;
            }
#pragma unroll
            for (int dk = 0; dk < 4; ++dk) {
                const float4 w0 = *(const float4*)&W1[(kk + dk) * HH + c0];
                const float4 w1 = *(const float4*)&W1[(kk + dk) * HH + c0 + 4];
#pragma unroll
                for (int r = 0; r < 4; ++r) {
                    const float av = af[r][dk];
                    acc[r][0] = fmaf(av, w0.x, acc[r][0]);
                    acc[r][1] = fmaf(av, w0.y, acc[r][1]);
                    acc[r][2] = fmaf(av, w0.z, acc[r][2]);
                    acc[r][3] = fmaf(av, w0.w, acc[r][3]);
                    acc[r][4] = fmaf(av, w1.x, acc[r][4]);
                    acc[r][5] = fmaf(av, w1.y, acc[r][5]);
                    acc[r][6] = fmaf(av, w1.z, acc[r][6]);
                    acc[r][7] = fmaf(av, w1.w, acc[r][7]);
                }
            }
        }

        float w2[8];
#pragma unroll
        for (int c = 0; c < 8; ++c) w2[c] = W2[c0 + c];
        float pz[4];
#pragma unroll
        for (int r = 0; r < 4; ++r) {
            float s = 0.f;
#pragma unroll
            for (int c = 0; c < 8; ++c) s = fmaf(fmaxf(acc[r][c], 0.f), w2[c], s);
            pz[r] = s;
        }
#pragma unroll
        for (int m = 1; m <= 16; m <<= 1) {
#pragma unroll
            for (int r = 0; r < 4; ++r) pz[r] += __shfl_xor(pz[r], m, 64);
        }
        if (colg == 0) {
#pragma unroll
            for (int r = 0; r < 4; ++r) zs[rowg * 4 + r] = pz[r] + b2v;
        }
        __syncthreads();

        if (tid < RT) {
            const int idx = T * RT + tid;
            if (idx < cnt) {
                const float z = zs[tid];
                if (fabsf(z) < TAU2) {
                    need64[tid] = 1;
                } else if (z > 0.f) {
                    const int e = eL[tid];
                    atomicMax(&last[srcIdx[e]], e + 1);
                    atomicMax(&last[dstIdx[e]], e + 1);
                }
            }
        }
        __syncthreads();

        for (int r = 0; r < RT; ++r) {
            if (!need64[r]) continue;          // wave-uniform branch
            const int j = tid;
            double h0 = 0.0, h1 = 0.0;
            for (int k = 0; k < K2D; k += 2) {
                h0 += (double)P[r * PST + k]     * (double)W1[(k)     * HH + j];
                h1 += (double)P[r * PST + k + 1] * (double)W1[(k + 1) * HH + j];
            }
            const double h = (double)b1[j] + h0 + h1;
            double v = (h > 0.0) ? h * (double)W2[j] : 0.0;
#pragma unroll
            for (int m = 1; m <= 32; m <<= 1) v += __shfl_xor(v, m, 64);
            if ((tid & 63) == 0) wsumd[tid >> 6] = v;
            __syncthreads();
            if (tid == 0) {
                const double z = wsumd[0] + wsumd[1] + wsumd[2] + wsumd[3] + (double)b2v;
                if (z > 0.0) {
                    const int e = eL[r];
                    atomicMax(&last[srcIdx[e]], e + 1);
                    atomicMax(&last[dstIdx[e]], e + 1);
                }
            }
            __syncthreads();
        }
        __syncthreads();
    }
}

// ---------------------------------------------------------------------------
// Resolver per NODE (winning edge only), both layers bf16 MFMA.
// ---------------------------------------------------------------------------
template<int BF>
__global__ __launch_bounds__(256) void res_kernel(
    const float* __restrict__ emb, const ushort* __restrict__ embbf,
    const int* __restrict__ srcIdx, const int* __restrict__ dstIdx,
    const ushort* __restrict__ w1s, const float* __restrict__ b1,
    const ushort* __restrict__ w2s, const float* __restrict__ b2,
    const int* __restrict__ last,
    float* __restrict__ outRes)
{
    __shared__ __align__(16) ushort A_lds[TE * K2D];
    __shared__ int lastL[TE];
    const int tid = threadIdx.x;
    const int n0 = blockIdx.x * TE;
    const int wv = tid >> 6;
    const int lane = tid & 63;

    if (tid < TE) {
        const int n = n0 + tid;
        lastL[tid] = (n < NN) ? last[n] : 0;
    }
    if (BF) {
        const int r = wv * 16 + (lane & 15);
        const int n = n0 + r;
        int e = 0;
        if (n < NN) { const int lv = last[n]; if (lv > 0) e = lv - 1; }
        const int ns = srcIdx[e], nd = dstIdx[e];
        const int ko = (lane >> 4) * 8;
#pragma unroll
        for (int s = 0; s < 8; ++s) {
            const int node = (s < 4) ? ns : nd;
            const ushort* g = embbf + (size_t)node * DD + (s & 3) * 32 + ko;
            __builtin_amdgcn_global_load_lds((const g1_void_t*)g,
                                             (lds_void_t*)&A_lds[(wv * 8 + s) * 512],
                                             16, 0, 0);
        }
    } else {
        const int r = tid >> 2, q = tid & 3;
        const int n = n0 + r;
        int e = 0;
        if (n < NN) { const int l = last[n]; if (l > 0) e = l - 1; }
        const int node = (q < 2) ? srcIdx[e] : dstIdx[e];
        const float4* s4 = (const float4*)(emb + (size_t)node * DD + (q & 1) * 64);
#pragma unroll
        for (int u = 0; u < 16; ++u) {
            const float4 v = s4[u];
            const int k0 = q * 64 + u * 4;
            uint2 p;
            p.x = (uint)f2bf(v.x) | ((uint)f2bf(v.y) << 16);
            p.y = (uint)f2bf(v.z) | ((uint)f2bf(v.w) << 16);
            *(uint2*)&A_lds[stageOff(r, k0)] = p;
        }
    }
    __syncthreads();

    const int lc = lane & 15, lg = lane >> 4;

    f32x4 acc[4][4] = {};
    {
        const ushort* wbase = w1s + (size_t)(wv * 4) * 8 * 512;
#pragma unroll 2
        for (int t = 0; t < 8; ++t) {
            bf16x8 af[4], bfr[4];
#pragma unroll
            for (int m = 0; m < 4; ++m)
                af[m] = *(const bf16x8*)&A_lds[(m * 8 + t) * 512 + lane * 8];
#pragma unroll
            for (int n = 0; n < 4; ++n)
                bfr[n] = *(const bf16x8*)(wbase + (n * 8 + t) * 512 + lane * 8);
#pragma unroll
            for (int m = 0; m < 4; ++m)
#pragma unroll
                for (int n = 0; n < 4; ++n)
                    acc[m][n] = __builtin_amdgcn_mfma_f32_16x16x32_bf16(af[m], bfr[n], acc[m][n], 0, 0, 0);
        }
    }
    float b1v[4];
#pragma unroll
    for (int n = 0; n < 4; ++n) b1v[n] = b1[wv * 64 + n * 16 + lc];

    __syncthreads();
#pragma unroll
    for (int m = 0; m < 4; ++m)
#pragma unroll
        for (int n = 0; n < 4; ++n) {
            const int hcol = wv * 64 + n * 16 + lc;
#pragma unroll
            for (int r = 0; r < 4; ++r) {
                const int row = m * 16 + lg * 4 + r;
                A_lds[stageOff(row, hcol)] = f2bf(fmaxf(acc[m][n][r] + b1v[n], 0.f));
            }
        }
    __syncthreads();

    f32x4 acc2[4][2] = {};
    {
        const ushort* wbase = w2s + (size_t)(wv * 2) * 8 * 512;
#pragma unroll 2
        for (int t = 0; t < 8; ++t) {
            bf16x8 af[4], bfr[2];
#pragma unroll
            for (int m = 0; m < 4; ++m)
                af[m] = *(const bf16x8*)&A_lds[(m * 8 + t) * 512 + lane * 8];
#pragma unroll
            for (int n = 0; n < 2; ++n)
                bfr[n] = *(const bf16x8*)(wbase + (n * 8 + t) * 512 + lane * 8);
#pragma unroll
            for (int m = 0; m < 4; ++m)
#pragma unroll
                for (int n = 0; n < 2; ++n)
                    acc2[m][n] = __builtin_amdgcn_mfma_f32_16x16x32_bf16(af[m], bfr[n], acc2[m][n], 0, 0, 0);
        }
    }
    float b2v[2];
#pragma unroll
    for (int n = 0; n < 2; ++n) b2v[n] = b2[(wv * 2 + n) * 16 + lc];

#pragma unroll
    for (int m = 0; m < 4; ++m)
#pragma unroll
        for (int r = 0; r < 4; ++r) {
            const int row = m * 16 + lg * 4 + r;
            const int n = n0 + row;
            if (n >= NN) continue;
            const bool hit = lastL[row] > 0;
#pragma unroll
            for (int c = 0; c < 2; ++c) {
                const int col = (wv * 2 + c) * 16 + lc;
                const float ev = emb[(size_t)n * DD + col];
                outRes[(size_t)n * DD + col] =
                    hit ? (ev + acc2[m][c][r] + b2v[c]) * 0.5f : ev;
            }
        }
}

// ---------------------------------------------------------------------------
extern "C" void kernel_launch(void* const* d_in, const int* in_sizes, int n_in,
                              void* d_out, int out_size, void* d_ws, size_t ws_size,
                              hipStream_t stream)
{
    const float* emb = (const float*)d_in[0];
    const int*   edge = (const int*)d_in[1];
    const float* Wd1 = (const float*)d_in[2];
    const float* bd1 = (const float*)d_in[3];
    const float* Wd2 = (const float*)d_in[4];
    const float* bd2 = (const float*)d_in[5];
    const float* Wr1 = (const float*)d_in[6];
    const float* br1 = (const float*)d_in[7];
    const float* Wr2 = (const float*)d_in[8];
    const float* br2 = (const float*)d_in[9];

    const int* srcIdx = edge;
    const int* dstIdx = edge + EE;

    float* outRes = (float*)d_out;
    float* scores = outRes + (size_t)NN * DD;

    // ws: last[50112] | flagCount | wd1s | wr1s | wr2s | flagList | embbf
    int* last = (int*)d_ws;
    int* flagCount = last + 50112;
    ushort* wd1s = (ushort*)(last + 50176);    // 128 KB
    ushort* wr1s = wd1s + 65536;               // 128 KB
    ushort* wr2s = wr1s + 65536;               // 64 KB
    int* flagList = (int*)(wr2s + 32768);      // 256 KB
    ushort* embbf = (ushort*)(flagList + 65536);   // 12.8 MB

    const size_t base   = 50176u * 4 + (65536u + 65536u + 32768u) * 2 + 65536u * 4;
    const size_t needBF = base + (size_t)NN * DD * 2;
    const int useBF = (ws_size >= needBF) ? 1 : 0;

    int flagCap = 65536;
    if (ws_size < base) {
        long avail = ((long)ws_size - (long)(base - 65536u * 4)) / 4;
        flagCap = avail < 0 ? 0 : (int)avail;
    }

    hipMemsetAsync(d_ws, 0, 50176 * sizeof(int), stream);   // last + flagCount

    prep_kernel<<<3205, 256, 0, stream>>>(emb, embbf, useBF,
                                          Wd1, wd1s, Wr1, wr1s, Wr2, wr2s);

    if (useBF) {
        det_pipe<<<DGRID, 256, 0, stream>>>(embbf, srcIdx, dstIdx,
                                            wd1s, bd1, Wd2, bd2,
                                            scores, last, flagCount, flagList, flagCap);
    } else {
        det_kernel<<<EE / TE, 256, 0, stream>>>(emb, srcIdx, dstIdx,
                                                wd1s, bd1, Wd2, bd2,
                                                scores, last, flagCount, flagList, flagCap);
    }
    refine_kernel<<<1024, 256, 0, stream>>>(emb, srcIdx, dstIdx,
                                            Wd1, bd1, Wd2, bd2,
                                            last, flagCount, flagList, flagCap);
    if (useBF) {
        res_kernel<1><<<(NN + TE - 1) / TE, 256, 0, stream>>>(emb, embbf, srcIdx, dstIdx,
                                                              wr1s, br1, wr2s, br2,
                                                              last, outRes);
    } else {
        res_kernel<0><<<(NN + TE - 1) / TE, 256, 0, stream>>>(emb, embbf, srcIdx, dstIdx,
                                                              wr1s, br1, wr2s, br2,
                                                              last, outRes);
    }
}

// Round 14
// 193.361 us; speedup vs baseline: 1.3184x; 1.3184x over previous
//
#include <hip/hip_runtime.h>
#include <math.h>

#define NN 50000      // nodes
#define DD 128        // embedding dim
#define K2D 256       // 2*D (pair width)
#define HH 256        // hidden
#define EE 400000     // edges
#define TE 64         // rows per block (det / res)
#define RT 32         // flagged edges per refine tile
#define PST 260       // padded fp32 LDS row stride
#define TAU  0.005f   // |z_bf16| band -> fp32 refine (sigma(dz)~4e-4, >=12 sigma)
#define TAU2 5e-5f    // |z_fp32| band -> fp64 decide (inline)
#define DGRID 512     // det_pipe persistent grid (2 blocks/CU at 66KB LDS)

typedef __attribute__((ext_vector_type(8))) short bf16x8;
typedef __attribute__((ext_vector_type(4))) float f32x4;
typedef unsigned int uint;
typedef unsigned short ushort;

typedef __attribute__((address_space(3))) void lds_void_t;
typedef __attribute__((address_space(1))) void g1_void_t;

__device__ __forceinline__ ushort f2bf(float x) {
    uint u = __builtin_bit_cast(uint, x);
    u = (u + 0x7FFFu + ((u >> 16) & 1u)) >> 16;   // RNE
    return (ushort)u;
}

// LDS A-tile in MFMA A-fragment order (round-2 derivation):
// (r,k) -> sid=(r>>4)*8+(k>>5), lane=((k>>3)&3)*16+(r&15), j=k&7
__device__ __forceinline__ int stageOff(int r, int k) {
    return ((r >> 4) * 8 + (k >> 5)) * 512 + ((((k >> 3) & 3) << 4) + (r & 15)) * 8 + (k & 7);
}

__device__ __forceinline__ void swz_unit(const float* __restrict__ W,
                                         ushort* __restrict__ out,
                                         int N, int Kt, int unit, int l)
{
    const int n = unit / Kt, t = unit - n * Kt;
    const int row0 = t * 32 + (l >> 4) * 8;
    const int col = n * 16 + (l & 15);
    ushort tmp[8];
#pragma unroll
    for (int j = 0; j < 8; ++j) tmp[j] = f2bf(W[(row0 + j) * N + col]);
    uint4 p;
    p.x = (uint)tmp[0] | ((uint)tmp[1] << 16);
    p.y = (uint)tmp[2] | ((uint)tmp[3] << 16);
    p.z = (uint)tmp[4] | ((uint)tmp[5] << 16);
    p.w = (uint)tmp[6] | ((uint)tmp[7] << 16);
    *(uint4*)(out + ((size_t)unit * 64 + l) * 8) = p;
}

// ---------------------------------------------------------------------------
// PREP: emb fp32->bf16 (blocks 0..3124) + weight swizzles (blocks 3125..3204)
// ---------------------------------------------------------------------------
__global__ __launch_bounds__(256) void prep_kernel(
    const float* __restrict__ emb, ushort* __restrict__ embbf, int doConv,
    const float* __restrict__ Wd1, ushort* __restrict__ wd1s,
    const float* __restrict__ Wr1, ushort* __restrict__ wr1s,
    const float* __restrict__ Wr2, ushort* __restrict__ wr2s)
{
    const int gid = blockIdx.x;
    const int tid = threadIdx.x;
    if (gid < 3125) {
        if (!doConv) return;
        const int i = gid * 256 + tid;            // 3125*256 == NN*DD/8 exactly
        const float4 a = ((const float4*)emb)[(size_t)i * 2];
        const float4 b = ((const float4*)emb)[(size_t)i * 2 + 1];
        uint4 p;
        p.x = (uint)f2bf(a.x) | ((uint)f2bf(a.y) << 16);
        p.y = (uint)f2bf(a.z) | ((uint)f2bf(a.w) << 16);
        p.z = (uint)f2bf(b.x) | ((uint)f2bf(b.y) << 16);
        p.w = (uint)f2bf(b.z) | ((uint)f2bf(b.w) << 16);
        *(uint4*)(embbf + (size_t)i * 8) = p;
        return;
    }
    const int sub = tid >> 6, l = tid & 63;
    if (gid < 3125 + 32) {
        swz_unit(Wd1, wd1s, HH, 8, (gid - 3125) * 4 + sub, l);
    } else if (gid < 3125 + 64) {
        swz_unit(Wr1, wr1s, HH, 8, (gid - 3125 - 32) * 4 + sub, l);
    } else {
        swz_unit(Wr2, wr2s, DD, 8, (gid - 3125 - 64) * 4 + sub, l);
    }
}

// ---------------------------------------------------------------------------
// PIPELINED persistent detector (T3/T4: counted vmcnt, raw barriers).
// 512 blocks x 4 waves; double-buffered A tiles; STAGE(T+1) stays in flight
// across the barrier (vmcnt(8), never 0 in steady state).
// FIFO: [STAGE(Tn) 8][B-loads][stores][STAGE(Tn+1) 8] -> vmcnt(8) leaves
// exactly STAGE(Tn+1) outstanding and drains all older ops. Race-free.
// Best measured det structure (108 us, round 11); TD=32 (175 us), reg-direct
// (170 us), persistent-B (303 us), UV (405 us), sorted (112 us) all worse.
// ---------------------------------------------------------------------------
__global__ __launch_bounds__(256) void det_pipe(
    const ushort* __restrict__ embbf,
    const int* __restrict__ srcIdx, const int* __restrict__ dstIdx,
    const ushort* __restrict__ w1s, const float* __restrict__ b1,
    const float* __restrict__ W2, const float* __restrict__ b2p,
    float* __restrict__ scores,
    int* __restrict__ last,
    int* __restrict__ flagCount, int* __restrict__ flagList, int flagCap)
{
    __shared__ __align__(16) ushort A[2][TE * K2D];   // 2 x 32 KB, frag order
    __shared__ float zp[2][256];
    const int tid = threadIdx.x;
    const int wv = tid >> 6;
    const int lane = tid & 63;
    const int lc = lane & 15, lg = lane >> 4;
    const int nT = EE / TE;                            // 6250
    const int stride = gridDim.x;

    float b1v[4], w2v[4];
#pragma unroll
    for (int n = 0; n < 4; ++n) {
        const int col = wv * 64 + n * 16 + lc;
        b1v[n] = b1[col];
        w2v[n] = W2[col];
    }
    const float b2v = *b2p;
    const ushort* wbase = w1s + (size_t)(wv * 4) * 8 * 512;

    // wave wv stages its own m-tile (rows wv*16..+15) into A[bp]
    auto STAGE = [&](int T, int bp) {
        const int e = T * TE + wv * 16 + lc;
        const int ns = srcIdx[e], nd = dstIdx[e];
        const int ko = lg * 8;
#pragma unroll
        for (int s = 0; s < 8; ++s) {
            const int node = (s < 4) ? ns : nd;
            const ushort* g = embbf + (size_t)node * DD + (s & 3) * 32 + ko;
            __builtin_amdgcn_global_load_lds((const g1_void_t*)g,
                                             (lds_void_t*)&A[bp][(wv * 8 + s) * 512],
                                             16, 0, 0);
        }
    };

    int T = blockIdx.x;
    int cur = 0;
    STAGE(T, 0);                                       // prologue: 8 in flight

    for (; T < nT; T += stride) {
        const int Tn = T + stride;
        if (Tn < nT) {
            STAGE(Tn, cur ^ 1);                        // +8 (newest)
            asm volatile("s_waitcnt vmcnt(8)" ::: "memory");   // tile T landed
        } else {
            asm volatile("s_waitcnt vmcnt(0)" ::: "memory");   // tail drain
        }
        __builtin_amdgcn_sched_barrier(0);
        __builtin_amdgcn_s_barrier();                  // all waves: A[cur] ready
        __builtin_amdgcn_sched_barrier(0);

        // ---- compute tile T from A[cur] ----
        f32x4 acc[4][4] = {};
#pragma unroll 2
        for (int t = 0; t < 8; ++t) {
            bf16x8 af[4], bfr[4];
#pragma unroll
            for (int m = 0; m < 4; ++m)
                af[m] = *(const bf16x8*)&A[cur][(m * 8 + t) * 512 + lane * 8];
#pragma unroll
            for (int n = 0; n < 4; ++n)
                bfr[n] = *(const bf16x8*)(wbase + (n * 8 + t) * 512 + lane * 8);
#pragma unroll
            for (int m = 0; m < 4; ++m)
#pragma unroll
                for (int n = 0; n < 4; ++n)
                    acc[m][n] = __builtin_amdgcn_mfma_f32_16x16x32_bf16(af[m], bfr[n], acc[m][n], 0, 0, 0);
        }

        float pz[4][4];
#pragma unroll
        for (int m = 0; m < 4; ++m)
#pragma unroll
            for (int r = 0; r < 4; ++r) {
                float s = 0.f;
#pragma unroll
                for (int n = 0; n < 4; ++n)
                    s = fmaf(fmaxf(acc[m][n][r] + b1v[n], 0.f), w2v[n], s);
                pz[m][r] = s;
            }
#pragma unroll
        for (int msk = 1; msk <= 8; msk <<= 1)
#pragma unroll
            for (int m = 0; m < 4; ++m)
#pragma unroll
                for (int r = 0; r < 4; ++r)
                    pz[m][r] += __shfl_xor(pz[m][r], msk, 64);
        if (lc == 0) {
#pragma unroll
            for (int m = 0; m < 4; ++m)
#pragma unroll
                for (int r = 0; r < 4; ++r)
                    zp[cur][wv * 64 + m * 16 + lg * 4 + r] = pz[m][r];
        }

        asm volatile("s_waitcnt lgkmcnt(0)" ::: "memory");     // zp visible
        __builtin_amdgcn_sched_barrier(0);
        __builtin_amdgcn_s_barrier();
        __builtin_amdgcn_sched_barrier(0);

        // ---- epilogue (wave 0) overlaps other waves' next STAGE ----
        if (tid < 64) {
            const int e = T * TE + tid;
            const float z = zp[cur][tid] + zp[cur][64 + tid] +
                            zp[cur][128 + tid] + zp[cur][192 + tid] + b2v;
            scores[e] = 1.0f / (1.0f + expf(-z));
            bool deferred = false;
            if (fabsf(z) < TAU) {
                const int slot = atomicAdd(flagCount, 1);
                if (slot < flagCap) { flagList[slot] = e; deferred = true; }
            }
            if (!deferred && z > 0.0f) {
                atomicMax(&last[srcIdx[e]], e + 1);
                atomicMax(&last[dstIdx[e]], e + 1);
            }
        }
        cur ^= 1;
    }
}

// ---------------------------------------------------------------------------
// Fallback detector (round-10 proven) for tiny workspaces.
// ---------------------------------------------------------------------------
__global__ __launch_bounds__(256) void det_kernel(
    const float* __restrict__ emb,
    const int* __restrict__ srcIdx, const int* __restrict__ dstIdx,
    const ushort* __restrict__ w1s, const float* __restrict__ b1,
    const float* __restrict__ W2, const float* __restrict__ b2p,
    float* __restrict__ scores,
    int* __restrict__ last,
    int* __restrict__ flagCount, int* __restrict__ flagList, int flagCap)
{
    __shared__ __align__(16) ushort A_lds[TE * K2D];
    __shared__ float zp[256];
    const int tid = threadIdx.x;
    const int e0 = blockIdx.x * TE;
    {
        const int r = tid >> 2, q = tid & 3;
        const int e = e0 + r;
        const int node = (q < 2) ? srcIdx[e] : dstIdx[e];
        const float4* s4 = (const float4*)(emb + (size_t)node * DD + (q & 1) * 64);
#pragma unroll
        for (int u = 0; u < 16; ++u) {
            const float4 v = s4[u];
            const int k0 = q * 64 + u * 4;
            uint2 p;
            p.x = (uint)f2bf(v.x) | ((uint)f2bf(v.y) << 16);
            p.y = (uint)f2bf(v.z) | ((uint)f2bf(v.w) << 16);
            *(uint2*)&A_lds[stageOff(r, k0)] = p;
        }
    }
    __syncthreads();

    const int wv = tid >> 6;
    const int lane = tid & 63;
    const int lc = lane & 15, lg = lane >> 4;

    f32x4 acc[4][4] = {};
    const ushort* wbase = w1s + (size_t)(wv * 4) * 8 * 512;
#pragma unroll 2
    for (int t = 0; t < 8; ++t) {
        bf16x8 af[4], bfr[4];
#pragma unroll
        for (int m = 0; m < 4; ++m)
            af[m] = *(const bf16x8*)&A_lds[(m * 8 + t) * 512 + lane * 8];
#pragma unroll
        for (int n = 0; n < 4; ++n)
            bfr[n] = *(const bf16x8*)(wbase + (n * 8 + t) * 512 + lane * 8);
#pragma unroll
        for (int m = 0; m < 4; ++m)
#pragma unroll
            for (int n = 0; n < 4; ++n)
                acc[m][n] = __builtin_amdgcn_mfma_f32_16x16x32_bf16(af[m], bfr[n], acc[m][n], 0, 0, 0);
    }
    float b1v[4], w2v[4];
#pragma unroll
    for (int n = 0; n < 4; ++n) {
        const int col = wv * 64 + n * 16 + lc;
        b1v[n] = b1[col];
        w2v[n] = W2[col];
    }
    float pz[4][4];
#pragma unroll
    for (int m = 0; m < 4; ++m)
#pragma unroll
        for (int r = 0; r < 4; ++r) {
            float s = 0.f;
#pragma unroll
            for (int n = 0; n < 4; ++n)
                s = fmaf(fmaxf(acc[m][n][r] + b1v[n], 0.f), w2v[n], s);
            pz[m][r] = s;
        }
#pragma unroll
    for (int msk = 1; msk <= 8; msk <<= 1)
#pragma unroll
        for (int m = 0; m < 4; ++m)
#pragma unroll
            for (int r = 0; r < 4; ++r)
                pz[m][r] += __shfl_xor(pz[m][r], msk, 64);
    if (lc == 0) {
#pragma unroll
        for (int m = 0; m < 4; ++m)
#pragma unroll
            for (int r = 0; r < 4; ++r)
                zp[wv * 64 + m * 16 + lg * 4 + r] = pz[m][r];
    }
    __syncthreads();
    if (tid < 64) {
        const int e = e0 + tid;
        const float z = zp[tid] + zp[64 + tid] + zp[128 + tid] + zp[192 + tid] + *b2p;
        scores[e] = 1.0f / (1.0f + expf(-z));
        bool deferred = false;
        if (fabsf(z) < TAU) {
            const int slot = atomicAdd(flagCount, 1);
            if (slot < flagCap) { flagList[slot] = e; deferred = true; }
        }
        if (!deferred && z > 0.0f) {
            atomicMax(&last[srcIdx[e]], e + 1);
            atomicMax(&last[dstIdx[e]], e + 1);
        }
    }
}

// ---------------------------------------------------------------------------
// Refine (fp32 tiled GEMM over flagged edges) + inline fp64 final decision.
// ---------------------------------------------------------------------------
__global__ __launch_bounds__(256) void refine_kernel(
    const float* __restrict__ emb,
    const int* __restrict__ srcIdx, const int* __restrict__ dstIdx,
    const float* __restrict__ W1, const float* __restrict__ b1,
    const float* __restrict__ W2, const float* __restrict__ b2p,
    int* __restrict__ last,
    const int* __restrict__ flagCount, const int* __restrict__ flagList,
    int flagCap)
{
    __shared__ __align__(16) float P[RT * PST];   // 33.3 KB
    __shared__ int eL[RT];
    __shared__ float zs[RT];
    __shared__ int need64[RT];
    __shared__ double wsumd[4];
    const int tid = threadIdx.x;
    const int cnt = min(*flagCount, flagCap);
    const int nTiles = (cnt + RT - 1) / RT;
    const float b2v = *b2p;

    for (int T = blockIdx.x; T < nTiles; T += gridDim.x) {
        if (tid < RT) {
            const int idx = T * RT + tid;
            eL[tid] = flagList[min(idx, cnt - 1)];
            need64[tid] = 0;
        }
        __syncthreads();
        {
            const int i = tid >> 3, q = tid & 7;
            const int e = eL[i];
            const int node = (q < 4) ? srcIdx[e] : dstIdx[e];
            const float4* s4 = (const float4*)(emb + (size_t)node * DD + (q & 3) * 32);
            float4* d4 = (float4*)(P + i * PST + q * 32);
#pragma unroll
            for (int t = 0; t < 8; ++t) d4[t] = s4[t];
        }
        __syncthreads();

        const int rowg = tid >> 5;
        const int colg = tid & 31;
        const int c0 = colg * 8;

        float acc[4][8];
#pragma unroll
        for (int c = 0; c < 8; ++c) {
            const float bv = b1[c0 + c];
#pragma unroll
            for (int r = 0; r < 4; ++r) acc[r][c] = bv;
        }
        for (int kk = 0; kk < K2D; kk += 4) {
            float af[4][4];
#pragma unroll
            for (int r = 0; r < 4; ++r) {
                const float4 v = *(const float4*)&P[(rowg * 4 + r) * PST + kk];
                af[r][0] = v.x; af[r][1] = v.y; af[r][2] = v.z; af[r][3] = v.w;
            }
#pragma unroll
            for (int dk = 0; dk < 4; ++dk) {
                const float4 w0 = *(const float4*)&W1[(kk + dk) * HH + c0];
                const float4 w1 = *(const float4*)&W1[(kk + dk) * HH + c0 + 4];
#pragma unroll
                for (int r = 0; r < 4; ++r) {
                    const float av = af[r][dk];
                    acc[r][0] = fmaf(av, w0.x, acc[r][0]);
                    acc[r][1] = fmaf(av, w0.y, acc[r][1]);
                    acc[r][2] = fmaf(av, w0.z, acc[r][2]);
                    acc[r][3] = fmaf(av, w0.w, acc[r][3]);
                    acc[r][4] = fmaf(av, w1.x, acc[r][4]);
                    acc[r][5] = fmaf(av, w1.y, acc[r][5]);
                    acc[r][6] = fmaf(av, w1.z, acc[r][6]);
                    acc[r][7] = fmaf(av, w1.w, acc[r][7]);
                }
            }
        }

        float w2[8];
#pragma unroll
        for (int c = 0; c < 8; ++c) w2[c] = W2[c0 + c];
        float pz[4];
#pragma unroll
        for (int r = 0; r < 4; ++r) {
            float s = 0.f;
#pragma unroll
            for (int c = 0; c < 8; ++c) s = fmaf(fmaxf(acc[r][c], 0.f), w2[c], s);
            pz[r] = s;
        }
#pragma unroll
        for (int m = 1; m <= 16; m <<= 1) {
#pragma unroll
            for (int r = 0; r < 4; ++r) pz[r] += __shfl_xor(pz[r], m, 64);
        }
        if (colg == 0) {
#pragma unroll
            for (int r = 0; r < 4; ++r) zs[rowg * 4 + r] = pz[r] + b2v;
        }
        __syncthreads();

        if (tid < RT) {
            const int idx = T * RT + tid;
            if (idx < cnt) {
                const float z = zs[tid];
                if (fabsf(z) < TAU2) {
                    need64[tid] = 1;
                } else if (z > 0.f) {
                    const int e = eL[tid];
                    atomicMax(&last[srcIdx[e]], e + 1);
                    atomicMax(&last[dstIdx[e]], e + 1);
                }
            }
        }
        __syncthreads();

        for (int r = 0; r < RT; ++r) {
            if (!need64[r]) continue;          // wave-uniform branch
            const int j = tid;
            double h0 = 0.0, h1 = 0.0;
            for (int k = 0; k < K2D; k += 2) {
                h0 += (double)P[r * PST + k]     * (double)W1[(k)     * HH + j];
                h1 += (double)P[r * PST + k + 1] * (double)W1[(k + 1) * HH + j];
            }
            const double h = (double)b1[j] + h0 + h1;
            double v = (h > 0.0) ? h * (double)W2[j] : 0.0;
#pragma unroll
            for (int m = 1; m <= 32; m <<= 1) v += __shfl_xor(v, m, 64);
            if ((tid & 63) == 0) wsumd[tid >> 6] = v;
            __syncthreads();
            if (tid == 0) {
                const double z = wsumd[0] + wsumd[1] + wsumd[2] + wsumd[3] + (double)b2v;
                if (z > 0.0) {
                    const int e = eL[r];
                    atomicMax(&last[srcIdx[e]], e + 1);
                    atomicMax(&last[dstIdx[e]], e + 1);
                }
            }
            __syncthreads();
        }
        __syncthreads();
    }
}

// ---------------------------------------------------------------------------
// Resolver per NODE (winning edge only), both layers bf16 MFMA.
// ---------------------------------------------------------------------------
template<int BF>
__global__ __launch_bounds__(256) void res_kernel(
    const float* __restrict__ emb, const ushort* __restrict__ embbf,
    const int* __restrict__ srcIdx, const int* __restrict__ dstIdx,
    const ushort* __restrict__ w1s, const float* __restrict__ b1,
    const ushort* __restrict__ w2s, const float* __restrict__ b2,
    const int* __restrict__ last,
    float* __restrict__ outRes)
{
    __shared__ __align__(16) ushort A_lds[TE * K2D];
    __shared__ int lastL[TE];
    const int tid = threadIdx.x;
    const int n0 = blockIdx.x * TE;
    const int wv = tid >> 6;
    const int lane = tid & 63;

    if (tid < TE) {
        const int n = n0 + tid;
        lastL[tid] = (n < NN) ? last[n] : 0;
    }
    if (BF) {
        const int r = wv * 16 + (lane & 15);
        const int n = n0 + r;
        int e = 0;
        if (n < NN) { const int lv = last[n]; if (lv > 0) e = lv - 1; }
        const int ns = srcIdx[e], nd = dstIdx[e];
        const int ko = (lane >> 4) * 8;
#pragma unroll
        for (int s = 0; s < 8; ++s) {
            const int node = (s < 4) ? ns : nd;
            const ushort* g = embbf + (size_t)node * DD + (s & 3) * 32 + ko;
            __builtin_amdgcn_global_load_lds((const g1_void_t*)g,
                                             (lds_void_t*)&A_lds[(wv * 8 + s) * 512],
                                             16, 0, 0);
        }
    } else {
        const int r = tid >> 2, q = tid & 3;
        const int n = n0 + r;
        int e = 0;
        if (n < NN) { const int l = last[n]; if (l > 0) e = l - 1; }
        const int node = (q < 2) ? srcIdx[e] : dstIdx[e];
        const float4* s4 = (const float4*)(emb + (size_t)node * DD + (q & 1) * 64);
#pragma unroll
        for (int u = 0; u < 16; ++u) {
            const float4 v = s4[u];
            const int k0 = q * 64 + u * 4;
            uint2 p;
            p.x = (uint)f2bf(v.x) | ((uint)f2bf(v.y) << 16);
            p.y = (uint)f2bf(v.z) | ((uint)f2bf(v.w) << 16);
            *(uint2*)&A_lds[stageOff(r, k0)] = p;
        }
    }
    __syncthreads();

    const int lc = lane & 15, lg = lane >> 4;

    f32x4 acc[4][4] = {};
    {
        const ushort* wbase = w1s + (size_t)(wv * 4) * 8 * 512;
#pragma unroll 2
        for (int t = 0; t < 8; ++t) {
            bf16x8 af[4], bfr[4];
#pragma unroll
            for (int m = 0; m < 4; ++m)
                af[m] = *(const bf16x8*)&A_lds[(m * 8 + t) * 512 + lane * 8];
#pragma unroll
            for (int n = 0; n < 4; ++n)
                bfr[n] = *(const bf16x8*)(wbase + (n * 8 + t) * 512 + lane * 8);
#pragma unroll
            for (int m = 0; m < 4; ++m)
#pragma unroll
                for (int n = 0; n < 4; ++n)
                    acc[m][n] = __builtin_amdgcn_mfma_f32_16x16x32_bf16(af[m], bfr[n], acc[m][n], 0, 0, 0);
        }
    }
    float b1v[4];
#pragma unroll
    for (int n = 0; n < 4; ++n) b1v[n] = b1[wv * 64 + n * 16 + lc];

    __syncthreads();
#pragma unroll
    for (int m = 0; m < 4; ++m)
#pragma unroll
        for (int n = 0; n < 4; ++n) {
            const int hcol = wv * 64 + n * 16 + lc;
#pragma unroll
            for (int r = 0; r < 4; ++r) {
                const int row = m * 16 + lg * 4 + r;
                A_lds[stageOff(row, hcol)] = f2bf(fmaxf(acc[m][n][r] + b1v[n], 0.f));
            }
        }
    __syncthreads();

    f32x4 acc2[4][2] = {};
    {
        const ushort* wbase = w2s + (size_t)(wv * 2) * 8 * 512;
#pragma unroll 2
        for (int t = 0; t < 8; ++t) {
            bf16x8 af[4], bfr[2];
#pragma unroll
            for (int m = 0; m < 4; ++m)
                af[m] = *(const bf16x8*)&A_lds[(m * 8 + t) * 512 + lane * 8];
#pragma unroll
            for (int n = 0; n < 2; ++n)
                bfr[n] = *(const bf16x8*)(wbase + (n * 8 + t) * 512 + lane * 8);
#pragma unroll
            for (int m = 0; m < 4; ++m)
#pragma unroll
                for (int n = 0; n < 2; ++n)
                    acc2[m][n] = __builtin_amdgcn_mfma_f32_16x16x32_bf16(af[m], bfr[n], acc2[m][n], 0, 0, 0);
        }
    }
    float b2v[2];
#pragma unroll
    for (int n = 0; n < 2; ++n) b2v[n] = b2[(wv * 2 + n) * 16 + lc];

#pragma unroll
    for (int m = 0; m < 4; ++m)
#pragma unroll
        for (int r = 0; r < 4; ++r) {
            const int row = m * 16 + lg * 4 + r;
            const int n = n0 + row;
            if (n >= NN) continue;
            const bool hit = lastL[row] > 0;
#pragma unroll
            for (int c = 0; c < 2; ++c) {
                const int col = (wv * 2 + c) * 16 + lc;
                const float ev = emb[(size_t)n * DD + col];
                outRes[(size_t)n * DD + col] =
                    hit ? (ev + acc2[m][c][r] + b2v[c]) * 0.5f : ev;
            }
        }
}

// ---------------------------------------------------------------------------
extern "C" void kernel_launch(void* const* d_in, const int* in_sizes, int n_in,
                              void* d_out, int out_size, void* d_ws, size_t ws_size,
                              hipStream_t stream)
{
    const float* emb = (const float*)d_in[0];
    const int*   edge = (const int*)d_in[1];
    const float* Wd1 = (const float*)d_in[2];
    const float* bd1 = (const float*)d_in[3];
    const float* Wd2 = (const float*)d_in[4];
    const float* bd2 = (const float*)d_in[5];
    const float* Wr1 = (const float*)d_in[6];
    const float* br1 = (const float*)d_in[7];
    const float* Wr2 = (const float*)d_in[8];
    const float* br2 = (const float*)d_in[9];

    const int* srcIdx = edge;
    const int* dstIdx = edge + EE;

    float* outRes = (float*)d_out;
    float* scores = outRes + (size_t)NN * DD;

    // ws: last[50112] | flagCount | wd1s | wr1s | wr2s | flagList | embbf
    int* last = (int*)d_ws;
    int* flagCount = last + 50112;
    ushort* wd1s = (ushort*)(last + 50176);    // 128 KB
    ushort* wr1s = wd1s + 65536;               // 128 KB
    ushort* wr2s = wr1s + 65536;               // 64 KB
    int* flagList = (int*)(wr2s + 32768);      // 256 KB
    ushort* embbf = (ushort*)(flagList + 65536);   // 12.8 MB

    const size_t base   = 50176u * 4 + (65536u + 65536u + 32768u) * 2 + 65536u * 4;
    const size_t needBF = base + (size_t)NN * DD * 2;
    const int useBF = (ws_size >= needBF) ? 1 : 0;

    int flagCap = 65536;
    if (ws_size < base) {
        long avail = ((long)ws_size - (long)(base - 65536u * 4)) / 4;
        flagCap = avail < 0 ? 0 : (int)avail;
    }

    hipMemsetAsync(d_ws, 0, 50176 * sizeof(int), stream);   // last + flagCount

    prep_kernel<<<3205, 256, 0, stream>>>(emb, embbf, useBF,
                                          Wd1, wd1s, Wr1, wr1s, Wr2, wr2s);

    if (useBF) {
        det_pipe<<<DGRID, 256, 0, stream>>>(embbf, srcIdx, dstIdx,
                                            wd1s, bd1, Wd2, bd2,
                                            scores, last, flagCount, flagList, flagCap);
    } else {
        det_kernel<<<EE / TE, 256, 0, stream>>>(emb, srcIdx, dstIdx,
                                                wd1s, bd1, Wd2, bd2,
                                                scores, last, flagCount, flagList, flagCap);
    }
    refine_kernel<<<1024, 256, 0, stream>>>(emb, srcIdx, dstIdx,
                                            Wd1, bd1, Wd2, bd2,
                                            last, flagCount, flagList, flagCap);
    if (useBF) {
        res_kernel<1><<<(NN + TE - 1) / TE, 256, 0, stream>>>(emb, embbf, srcIdx, dstIdx,
                                                              wr1s, br1, wr2s, br2,
                                                              last, outRes);
    } else {
        res_kernel<0><<<(NN + TE - 1) / TE, 256, 0, stream>>>(emb, embbf, srcIdx, dstIdx,
                                                              wr1s, br1, wr2s, br2,
                                                              last, outRes);
    }
}